// Round 7
// baseline (751.101 us; speedup 1.0000x reference)
//
#include <hip/hip_runtime.h>
#include <stdint.h>

#define B_ 64
#define S_ 512
#define K_ 1024
#define H_ 4096
#define C_ 32

typedef float  f32x4   __attribute__((ext_vector_type(4)));
typedef float  f32x16  __attribute__((ext_vector_type(16)));
typedef short  bf16x8  __attribute__((ext_vector_type(8)));
typedef unsigned short u16x8 __attribute__((ext_vector_type(8)));
typedef __attribute__((address_space(3))) unsigned int as3u32;
typedef const __attribute__((address_space(1))) unsigned int as1u32;

__device__ __forceinline__ unsigned short f2bf(float f) {
    unsigned u = __builtin_bit_cast(unsigned, f);
    u += 0x7fffu + ((u >> 16) & 1u);   // RNE
    return (unsigned short)(u >> 16);
}

// ---------------------------------------------------------------------------
// cat_ids may arrive as int32 or int64; detect on-device, normalize to i32.
__global__ void fix_cat_kernel(const void* __restrict__ cat_raw, int* __restrict__ cat32) {
    int t = threadIdx.x;                       // 64 threads = 1 wave
    const long long* c64 = (const long long*)cat_raw;
    const int*       c32 = (const int*)cat_raw;
    long long v = (t < 32) ? c64[t] : 0;
    int bad = (t < 32) && (v < 0 || v >= C_);
    unsigned long long m = __ballot(bad);
    if (m == 0ULL) {
        cat32[t] = (int)c64[t];
    } else {
        cat32[t] = c32[t];
    }
}

// ---------------------------------------------------------------------------
// x f32 -> bf16, vectorized 8 elems/thread
__global__ __launch_bounds__(256) void cvt_x_kernel(const float4* __restrict__ x,
                                                    uint4* __restrict__ xb, int n8) {
    int stride = gridDim.x * blockDim.x;
    for (int i = blockIdx.x * blockDim.x + threadIdx.x; i < n8; i += stride) {
        float4 a = x[2 * i], b = x[2 * i + 1];
        uint4 o;
        o.x = (unsigned)f2bf(a.x) | ((unsigned)f2bf(a.y) << 16);
        o.y = (unsigned)f2bf(a.z) | ((unsigned)f2bf(a.w) << 16);
        o.z = (unsigned)f2bf(b.x) | ((unsigned)f2bf(b.y) << 16);
        o.w = (unsigned)f2bf(b.z) | ((unsigned)f2bf(b.w) << 16);
        xb[i] = o;
    }
}

// ---------------------------------------------------------------------------
// W [C][K][H] f32 -> WT [C][H][K] bf16, LDS-tiled 64x64 transpose
__global__ __launch_bounds__(256) void cvt_w_kernel(const float* __restrict__ W,
                                                    unsigned short* __restrict__ WT) {
    __shared__ unsigned short tile[64 * 68];   // [k][n], padded stride 68
    const int nt = blockIdx.x;                 // 64 n-tiles
    const int kt = blockIdx.y;                 // 16 k-tiles
    const int c  = blockIdx.z;                 // 32 categories
    const int t  = threadIdx.x;

    const float* Wp = W + ((size_t)c << 22);
#pragma unroll
    for (int p = 0; p < 4; ++p) {
        int task = p * 256 + t;
        int kr = task >> 4;
        int nc = (task & 15) << 2;
        float4 v = *(const float4*)(Wp + (size_t)(kt * 64 + kr) * H_ + nt * 64 + nc);
        tile[kr * 68 + nc + 0] = f2bf(v.x);
        tile[kr * 68 + nc + 1] = f2bf(v.y);
        tile[kr * 68 + nc + 2] = f2bf(v.z);
        tile[kr * 68 + nc + 3] = f2bf(v.w);
    }
    __syncthreads();

    unsigned short* WTp = WT + ((size_t)c << 22);
#pragma unroll
    for (int q = 0; q < 2; ++q) {
        int task = q * 256 + t;
        int nl = task >> 3;
        int ko = (task & 7) << 3;
        u16x8 o;
#pragma unroll
        for (int j = 0; j < 8; ++j) o[j] = tile[(ko + j) * 68 + nl];
        *(u16x8*)(WTp + (size_t)(nt * 64 + nl) * K_ + kt * 64 + ko) = o;
    }
}

// ---------------------------------------------------------------------------
// Batched GEMM, register-pipelined 32x32x16 MFMA version.
//   256x256 tile, BK=32 (32 K-tiles, 2 k-steps of 16 each), 8 waves (2Mx4N),
//   per-wave 128x64 = 4x2 frags of 32x32 (acc 8 x f32x16 = 128 regs).
//   3-slot LDS ring (96 KiB), stage distance 2, ONE barrier + ONE counted
//   vmcnt(2) per K-tile.
//   KEY CHANGE vs rounds 2-6: each k-step's MFMA consumes regs loaded one
//   step EARLIER; the next step's 6 ds_read_b128 issue BEFORE the MFMA
//   cluster, guarded by counted lgkmcnt(6) (DS completes in-order) -> LDS
//   reads overlap the MFMA pipe instead of serializing with it.
//   Race proofs (per-wave lgkmcnt(0) at s1 is placed where it's already
//   satisfied, ~260cyc after issue):
//    - stage SA/SB(T+2)->slot (T-1)%3: its readers drained at T-1 s1
//      lgkmcnt(0), before the T-1 barrier, before this issue.
//    - reads of slot T+1 at s1: vmcnt(2) drains SA/SB(T+1) (issued T-1),
//      then barrier -> cross-wave landed.
//   Swizzle identical to round 6 (verified: 0 bank conflicts, correct).
__global__ __launch_bounds__(512, 2) void gemm5_kernel(
    const unsigned short* __restrict__ xb,   // [B][S][K] bf16
    const unsigned short* __restrict__ WT,   // [C][H][K] bf16
    const float* __restrict__ bias,          // [C][H]
    const int* __restrict__ cat,             // [B]
    float* __restrict__ out)                 // [B][S][H]
{
    extern __shared__ __align__(16) char smem[];   // 3 slots x (A 16K | B 16K)

    const int t    = threadIdx.x;
    const int lane = t & 63;
    const int w    = t >> 6;            // 0..7
    const int wm   = w >> 2;            // 0..1
    const int wn   = w & 3;             // 0..3
    const int l31  = lane & 31;
    const int hi2  = lane >> 5;         // 0..1 (k-octet)
    const int x2   = (l31 >> 1) & 3;    // row-pair swizzle term

    // XCD-aware bijective swizzle (2048 % 8 == 0); round-2 decode (good FETCH)
    const int wg = (blockIdx.x & 7) * 256 + (blockIdx.x >> 3);
    const int bn = wg & 15;
    const int bm = (wg >> 4) & 1;
    const int bb = wg >> 5;

    const int c = cat[bb];

    const unsigned short* Ap = xb + (size_t)bb * (S_ * K_) + (size_t)(bm * 256) * K_;
    const unsigned short* Bp = WT + (size_t)c * ((size_t)H_ * K_) + (size_t)(bn * 256) * K_;

    // staging: region = 256 rows x 64 B (16 KiB); wave w covers chunks w, 8+w
    // (16 rows each). LDS dest linear; global source pre-swizzled (m173):
    // logical 16B-slot = (lane&3) ^ ((row>>1)&3) = (lane&3) ^ ((lane>>3)&3).
    const int srow  = lane >> 2;
    const int sslot = (lane & 3) ^ ((lane >> 3) & 3);
    const char* sA0 = (const char*)(Ap + (size_t)((0 * 8 + w) * 16 + srow) * K_) + sslot * 16;
    const char* sA1 = (const char*)(Ap + (size_t)((1 * 8 + w) * 16 + srow) * K_) + sslot * 16;
    const char* sB0 = (const char*)(Bp + (size_t)((0 * 8 + w) * 16 + srow) * K_) + sslot * 16;
    const char* sB1 = (const char*)(Bp + (size_t)((1 * 8 + w) * 16 + srow) * K_) + sslot * 16;
    const int dc0 = (0 * 8 + w) * 1024;
    const int dc1 = (1 * 8 + w) * 1024;

    // fragment read bases: row stride 64 B; phys slot = logical ^ x2.
    // 32x32x16 A/B frag: lane holds [row = base + l31][k-octet hi2] (8 bf16).
    int aB[4], bB[2];
#pragma unroll
    for (int mi = 0; mi < 4; ++mi) aB[mi] = (wm * 128 + mi * 32 + l31) * 64;
#pragma unroll
    for (int ni = 0; ni < 2; ++ni) bB[ni] = 16384 + (wn * 64 + ni * 32 + l31) * 64;
    const int so0 = ((0 * 2 + hi2) ^ x2) << 4;   // k-step 0 slot byte
    const int so1 = ((1 * 2 + hi2) ^ x2) << 4;   // k-step 1 slot byte

    f32x16 acc[4][2];
#pragma unroll
    for (int mi = 0; mi < 4; ++mi)
#pragma unroll
        for (int ni = 0; ni < 2; ++ni)
#pragma unroll
            for (int e = 0; e < 16; ++e) acc[mi][ni][e] = 0.f;

#define GLD(src_, dst_) __builtin_amdgcn_global_load_lds((as1u32*)(src_), (as3u32*)(dst_), 16, 0, 0)
#define SA(tl_, sp_) do { const int o_ = (tl_) * 64;                              \
    GLD(sA0 + o_, (sp_) + dc0); GLD(sA1 + o_, (sp_) + dc1); } while (0)
#define SB(tl_, sp_) do { const int o_ = (tl_) * 64;                              \
    GLD(sB0 + o_, (sp_) + 16384 + dc0); GLD(sB1 + o_, (sp_) + 16384 + dc1); } while (0)
#define RD6(p_, so_, ra_, rb_) do {                                               \
    ra_[0] = *(const bf16x8*)((p_) + aB[0] + (so_));                              \
    ra_[1] = *(const bf16x8*)((p_) + aB[1] + (so_));                              \
    ra_[2] = *(const bf16x8*)((p_) + aB[2] + (so_));                              \
    ra_[3] = *(const bf16x8*)((p_) + aB[3] + (so_));                              \
    rb_[0] = *(const bf16x8*)((p_) + bB[0] + (so_));                              \
    rb_[1] = *(const bf16x8*)((p_) + bB[1] + (so_));                              \
} while (0)
#define MFMA8(ra_, rb_) do {                                                      \
    _Pragma("unroll")                                                             \
    for (int mi = 0; mi < 4; ++mi)                                                \
        _Pragma("unroll")                                                         \
        for (int ni = 0; ni < 2; ++ni)                                            \
            acc[mi][ni] = __builtin_amdgcn_mfma_f32_32x32x16_bf16(                \
                rb_[ni], ra_[mi], acc[mi][ni], 0, 0, 0);                          \
} while (0)

    char* p0 = smem;                 // slot holding tile T
    char* p1 = smem + 32768;         // tile T+1
    char* p2 = smem + 65536;         // staging target (tile T+2)

    // prologue: stage tiles 0,1 (8 gloads); tile-0 landed via vmcnt(4).
    SA(0, p0); SB(0, p0);
    SA(1, p1); SB(1, p1);
    asm volatile("s_waitcnt vmcnt(4)" ::: "memory");
    __builtin_amdgcn_s_barrier();

    bf16x8 pa[4], pb[2], qa[4], qb[2];
    RD6(p0, so0, pa, pb);            // regs for tile 0, k-step 0

#pragma unroll 1
    for (int T = 0; T < 32; ++T) {
        const int tl2 = (T + 2) & 31;          // tail wraps into dead slots

        // ---- s0: read k-step1 regs || stage A(T+2) || MFMA k-step0
        RD6(p0, so1, qa, qb);
        SA(tl2, p2);
        asm volatile("s_waitcnt lgkmcnt(6)" ::: "memory");   // pa/pb ready
        __builtin_amdgcn_sched_barrier(0);
        __builtin_amdgcn_s_setprio(1);
        MFMA8(pa, pb);
        __builtin_amdgcn_s_setprio(0);

        // ---- s1: drain own reads (already done) -> tile boundary -> read
        //      next tile's k-step0 regs || stage B(T+2) || MFMA k-step1
        asm volatile("s_waitcnt lgkmcnt(0)" ::: "memory");   // qa/qb done (cheap)
        __builtin_amdgcn_sched_barrier(0);
        asm volatile("s_waitcnt vmcnt(2)" ::: "memory");     // tile T+1 landed
        __builtin_amdgcn_s_barrier();
        RD6(p1, so0, pa, pb);
        SB(tl2, p2);
        asm volatile("s_waitcnt lgkmcnt(6)" ::: "memory");   // qa/qb ready (no-op)
        __builtin_amdgcn_sched_barrier(0);
        __builtin_amdgcn_s_setprio(1);
        MFMA8(qa, qb);
        __builtin_amdgcn_s_setprio(0);

        // rotate ring
        char* tmp = p0; p0 = p1; p1 = p2; p2 = tmp;
    }
#undef MFMA8
#undef RD6
#undef SB
#undef SA
#undef GLD

    // drain wrap-staged loads + dead reads before block exit
    asm volatile("s_waitcnt vmcnt(0) lgkmcnt(0)" ::: "memory");

    // epilogue. Swapped-operand D layout (32x32): m = l31,
    // n = (reg&3) + 8*(reg>>2) + 4*hi2  -> regs 4g..4g+3 cover n = 8g+4hi2 ..+3
    float* outp = out + ((size_t)bb * S_ + bm * 256 + wm * 128) * H_ + bn * 256 + wn * 64;
    const float* bp = bias + (size_t)c * H_ + bn * 256 + wn * 64;
#pragma unroll
    for (int mi = 0; mi < 4; ++mi) {
        float* orow = outp + (size_t)(mi * 32 + l31) * H_;
#pragma unroll
        for (int ni = 0; ni < 2; ++ni) {
#pragma unroll
            for (int g = 0; g < 4; ++g) {
                const int nf = ni * 32 + 8 * g + 4 * hi2;
                const f32x4 b4 = *(const f32x4*)(bp + nf);
                f32x4 v;
                v.x = acc[mi][ni][4 * g + 0] + b4.x;
                v.y = acc[mi][ni][4 * g + 1] + b4.y;
                v.z = acc[mi][ni][4 * g + 2] + b4.z;
                v.w = acc[mi][ni][4 * g + 3] + b4.w;
                __builtin_nontemporal_store(v, (f32x4*)(orow + nf));
            }
        }
    }
}

// ---------------------------------------------------------------------------
// Fallback (ws too small): correct but slow f32 vector-ALU kernel.
__global__ __launch_bounds__(256) void fallback_kernel(
    const float* __restrict__ x, const int* __restrict__ cat,
    const float* __restrict__ W, const float* __restrict__ bias,
    float* __restrict__ out)
{
    __shared__ float xs[K_];
    int bs = blockIdx.x;
    int bb = bs >> 9;
    int c  = cat[bb];
    const float* xp = x + (size_t)bs * K_;
    for (int i = threadIdx.x; i < K_ / 4; i += 256)
        ((float4*)xs)[i] = ((const float4*)xp)[i];
    __syncthreads();

    int h = blockIdx.y * 1024 + threadIdx.x * 4;
    const float* Wp = W + (size_t)c * K_ * H_ + h;
    float a0 = 0.f, a1 = 0.f, a2 = 0.f, a3 = 0.f;
    for (int k = 0; k < K_; ++k) {
        float xv = xs[k];
        float4 wv = *(const float4*)(Wp + (size_t)k * H_);
        a0 += xv * wv.x; a1 += xv * wv.y; a2 += xv * wv.z; a3 += xv * wv.w;
    }
    float4 bv = *(const float4*)(bias + c * H_ + h);
    float4 o; o.x = a0 + bv.x; o.y = a1 + bv.y; o.z = a2 + bv.z; o.w = a3 + bv.w;
    *(float4*)(out + (size_t)bs * H_ + h) = o;
}

// ---------------------------------------------------------------------------
extern "C" void kernel_launch(void* const* d_in, const int* in_sizes, int n_in,
                              void* d_out, int out_size, void* d_ws, size_t ws_size,
                              hipStream_t stream) {
    const float* x        = (const float*)d_in[0];
    const void*  cat_raw  = d_in[1];
    const float* W        = (const float*)d_in[2];
    const float* bias     = (const float*)d_in[3];
    float*       out      = (float*)d_out;

    const size_t CAT_BYTES = 256;
    const size_t XB_OFF    = 256;
    const size_t XB_BYTES  = (size_t)B_ * S_ * K_ * 2;          // 64 MiB
    const size_t WT_OFF    = XB_OFF + XB_BYTES;
    const size_t WT_BYTES  = (size_t)C_ * H_ * K_ * 2;          // 256 MiB
    const size_t NEED      = WT_OFF + WT_BYTES;

    const int* catp;
    if (ws_size >= CAT_BYTES) {
        int* cat32 = (int*)d_ws;
        fix_cat_kernel<<<1, 64, 0, stream>>>(cat_raw, cat32);
        catp = cat32;
    } else {
        catp = (const int*)cat_raw;
    }

    if (ws_size >= NEED) {
        unsigned short* xb = (unsigned short*)((char*)d_ws + XB_OFF);
        unsigned short* WT = (unsigned short*)((char*)d_ws + WT_OFF);
        cvt_x_kernel<<<2048, 256, 0, stream>>>((const float4*)x, (uint4*)xb,
                                               (int)((size_t)B_ * S_ * K_ / 8));
        dim3 gw(64, 16, 32);
        cvt_w_kernel<<<gw, 256, 0, stream>>>(W, WT);
        hipFuncSetAttribute((const void*)gemm5_kernel,
                            hipFuncAttributeMaxDynamicSharedMemorySize, 98304);
        gemm5_kernel<<<2048, 512, 98304, stream>>>(xb, WT, bias, catp, out);
    } else {
        dim3 g(B_ * S_, H_ / 1024);
        fallback_kernel<<<g, 256, 0, stream>>>(x, catp, W, bias, out);
    }
}

// Round 9
// 536.784 us; speedup vs baseline: 1.3993x; 1.3993x over previous
//
#include <hip/hip_runtime.h>
#include <stdint.h>

#define B_ 64
#define S_ 512
#define K_ 1024
#define H_ 4096
#define C_ 32

typedef float  f32x4  __attribute__((ext_vector_type(4)));
typedef short  bf16x8 __attribute__((ext_vector_type(8)));
typedef unsigned short u16x8 __attribute__((ext_vector_type(8)));
typedef __attribute__((address_space(3))) unsigned int as3u32;
typedef const __attribute__((address_space(1))) unsigned int as1u32;

__device__ __forceinline__ unsigned short f2bf(float f) {
    unsigned u = __builtin_bit_cast(unsigned, f);
    u += 0x7fffu + ((u >> 16) & 1u);   // RNE
    return (unsigned short)(u >> 16);
}

// ---------------------------------------------------------------------------
// cat_ids may arrive as int32 or int64; detect on-device, normalize to i32.
__global__ void fix_cat_kernel(const void* __restrict__ cat_raw, int* __restrict__ cat32) {
    int t = threadIdx.x;                       // 64 threads = 1 wave
    const long long* c64 = (const long long*)cat_raw;
    const int*       c32 = (const int*)cat_raw;
    long long v = (t < 32) ? c64[t] : 0;
    int bad = (t < 32) && (v < 0 || v >= C_);
    unsigned long long m = __ballot(bad);
    if (m == 0ULL) {
        cat32[t] = (int)c64[t];
    } else {
        cat32[t] = c32[t];
    }
}

// ---------------------------------------------------------------------------
// x f32 -> bf16, vectorized 8 elems/thread
__global__ __launch_bounds__(256) void cvt_x_kernel(const float4* __restrict__ x,
                                                    uint4* __restrict__ xb, int n8) {
    int stride = gridDim.x * blockDim.x;
    for (int i = blockIdx.x * blockDim.x + threadIdx.x; i < n8; i += stride) {
        float4 a = x[2 * i], b = x[2 * i + 1];
        uint4 o;
        o.x = (unsigned)f2bf(a.x) | ((unsigned)f2bf(a.y) << 16);
        o.y = (unsigned)f2bf(a.z) | ((unsigned)f2bf(a.w) << 16);
        o.z = (unsigned)f2bf(b.x) | ((unsigned)f2bf(b.y) << 16);
        o.w = (unsigned)f2bf(b.z) | ((unsigned)f2bf(b.w) << 16);
        xb[i] = o;
    }
}

// ---------------------------------------------------------------------------
// W [C][K][H] f32 -> WT [C][H][K] bf16, LDS-tiled 64x64 transpose
__global__ __launch_bounds__(256) void cvt_w_kernel(const float* __restrict__ W,
                                                    unsigned short* __restrict__ WT) {
    __shared__ unsigned short tile[64 * 68];   // [k][n], padded stride 68
    const int nt = blockIdx.x;                 // 64 n-tiles
    const int kt = blockIdx.y;                 // 16 k-tiles
    const int c  = blockIdx.z;                 // 32 categories
    const int t  = threadIdx.x;

    const float* Wp = W + ((size_t)c << 22);
#pragma unroll
    for (int p = 0; p < 4; ++p) {
        int task = p * 256 + t;
        int kr = task >> 4;
        int nc = (task & 15) << 2;
        float4 v = *(const float4*)(Wp + (size_t)(kt * 64 + kr) * H_ + nt * 64 + nc);
        tile[kr * 68 + nc + 0] = f2bf(v.x);
        tile[kr * 68 + nc + 1] = f2bf(v.y);
        tile[kr * 68 + nc + 2] = f2bf(v.z);
        tile[kr * 68 + nc + 3] = f2bf(v.w);
    }
    __syncthreads();

    unsigned short* WTp = WT + ((size_t)c << 22);
#pragma unroll
    for (int q = 0; q < 2; ++q) {
        int task = q * 256 + t;
        int nl = task >> 3;
        int ko = (task & 7) << 3;
        u16x8 o;
#pragma unroll
        for (int j = 0; j < 8; ++j) o[j] = tile[(ko + j) * 68 + nl];
        *(u16x8*)(WTp + (size_t)(nt * 64 + nl) * K_ + kt * 64 + ko) = o;
    }
}

// ---------------------------------------------------------------------------
// Batched GEMM, "compiler-scheduled" phase version.
//   256x256 tile, BK=32 (32 K-tiles), 8 waves (2Mx4N), per-wave 128x64
//   (acc = 8x4 of 16x16 frags = 128 regs). 3-slot LDS ring (96 KiB),
//   stage distance 2 tiles, ONE counted vmcnt(4) per K-tile (never 0).
//   2 phases/tile: {reads || 2 gload_lds -> s_barrier -> setprio -> 16 MFMA}.
// KEY CHANGE vs rounds 2-7: NO asm lgkmcnt, NO sched_barrier anywhere in the
//   loop. The compiler inserts minimal lgkmcnt for ds_read->MFMA deps (m97
//   behavior) and schedules freely; hand-pinning was the m141 failure mode.
// Race proofs (1 barrier/phase suffices):
//   - reads(slot r) vs stages(slot w=(T+2)%3, holds T-1): different slots.
//   - stage overwrite of slot w: its last reader consumed data before its
//     phase's MFMA (compiler waitcnt), which precedes that wave reaching the
//     NEXT barrier; stages issue >= 2 barriers later -> safe with no drain.
//   - tile T+1 landed: loads retire in order; at T-ph2 vmcnt(4) the only 4
//     outstanding are tile T+2's -> all of T+1's complete before the barrier.
// (Round-8 fix: slot pointers computed arithmetically — a pointer ARRAY
//  initialized from extern __shared__ hits "unsupported expression in
//  static initializer" addrspacecast on gfx950.)
__global__ __launch_bounds__(512, 2) void gemm6_kernel(
    const unsigned short* __restrict__ xb,   // [B][S][K] bf16
    const unsigned short* __restrict__ WT,   // [C][H][K] bf16
    const float* __restrict__ bias,          // [C][H]
    const int* __restrict__ cat,             // [B]
    float* __restrict__ out)                 // [B][S][H]
{
    extern __shared__ __align__(16) char smem[];   // 3 slots x (A 16K | B 16K)

    const int t    = threadIdx.x;
    const int lane = t & 63;
    const int w    = t >> 6;            // 0..7
    const int wm   = w >> 2;            // 0..1
    const int wn   = w & 3;             // 0..3
    const int lo   = lane & 15;
    const int hi   = lane >> 4;         // 0..3

    // XCD-aware bijective swizzle (2048 % 8 == 0)
    const int wg = (blockIdx.x & 7) * 256 + (blockIdx.x >> 3);
    const int bn = wg & 15;
    const int bm = (wg >> 4) & 1;
    const int bb = wg >> 5;

    const int c = cat[bb];

    const unsigned short* Ap = xb + (size_t)bb * (S_ * K_) + (size_t)(bm * 256) * K_;
    const unsigned short* Bp = WT + (size_t)c * ((size_t)H_ * K_) + (size_t)(bn * 256) * K_;

    // staging: one gload_lds per wave covers 16 rows x 64 B (1 KiB).
    // A tile (256 rows x 32 k x 2B = 16 KiB) = 2 block-wide gloads (A0: rows
    // 0-127 = chunk w, A1: rows 128-255 = chunk 8+w); same for B.
    // LDS dest linear (row = ch*16 + lane>>2, phys 16B-slot = lane&3); global
    // source pre-swizzled (m173): logical slot = (lane&3) ^ ((row>>1)&3)
    //                                          = (lane&3) ^ ((lane>>3)&3).
    const int srow  = lane >> 2;
    const int sslot = (lane & 3) ^ ((lane >> 3) & 3);
    const char* sA0 = (const char*)(Ap + (size_t)((0 * 8 + w) * 16 + srow) * K_) + sslot * 16;
    const char* sA1 = (const char*)(Ap + (size_t)((1 * 8 + w) * 16 + srow) * K_) + sslot * 16;
    const char* sB0 = (const char*)(Bp + (size_t)((0 * 8 + w) * 16 + srow) * K_) + sslot * 16;
    const char* sB1 = (const char*)(Bp + (size_t)((1 * 8 + w) * 16 + srow) * K_) + sslot * 16;
    const int dc0 = (0 * 8 + w) * 1024;
    const int dc1 = (1 * 8 + w) * 1024;

    // fragment read offsets (verified round 6: 0 bank conflicts):
    // row stride 64 B, phys slot = hi ^ ((row>>1)&3); frag bases are
    // multiples of 16 rows so (row>>1)&3 == (lo>>1)&3.
    const int xslot = (hi ^ ((lo >> 1) & 3)) << 4;
    int aoff[8], boff[4];
#pragma unroll
    for (int mi = 0; mi < 8; ++mi) aoff[mi] = (wm * 128 + mi * 16 + lo) * 64 + xslot;
#pragma unroll
    for (int ni = 0; ni < 4; ++ni) boff[ni] = 16384 + (wn * 64 + ni * 16 + lo) * 64 + xslot;

    f32x4 acc[8][4];
#pragma unroll
    for (int mi = 0; mi < 8; ++mi)
#pragma unroll
        for (int ni = 0; ni < 4; ++ni) acc[mi][ni] = f32x4{0.f, 0.f, 0.f, 0.f};

#define GLD(src_, dst_) __builtin_amdgcn_global_load_lds((as1u32*)(src_), (as3u32*)(dst_), 16, 0, 0)

    // prologue: stage K-tiles 0,1 into slots 0,1 (8 gloads); tile-0 landed
    // via counted vmcnt(4) (tile 1's 4 stay in flight).
    {
        char* s0 = smem;
        char* s1 = smem + 32768;
        GLD(sA0 + 0,  s0 + dc0);          GLD(sB0 + 0,  s0 + 16384 + dc0);
        GLD(sA1 + 0,  s0 + dc1);          GLD(sB1 + 0,  s0 + 16384 + dc1);
        GLD(sA0 + 64, s1 + dc0);          GLD(sB0 + 64, s1 + 16384 + dc0);
        GLD(sA1 + 64, s1 + dc1);          GLD(sB1 + 64, s1 + 16384 + dc1);
    }
    asm volatile("s_waitcnt vmcnt(4)" ::: "memory");
    __builtin_amdgcn_s_barrier();

    int rs = 0;   // read slot  = T % 3
    int ws = 2;   // write slot = (T+2) % 3

#pragma unroll 1
    for (int T = 0; T < 32; ++T) {
        const char* rb = smem + rs * 32768;
        char*       wb = smem + ws * 32768;
        const int soff = ((T + 2) & 31) * 64;   // tail wraps into dead slots
        bf16x8 av[4], bv[4], aw[4];

        // ---- ph1: read A-frags 0-3 + all B; stage A0,B0 of tile T+2
#pragma unroll
        for (int mi = 0; mi < 4; ++mi) av[mi] = *(const bf16x8*)(rb + aoff[mi]);
#pragma unroll
        for (int ni = 0; ni < 4; ++ni) bv[ni] = *(const bf16x8*)(rb + boff[ni]);
        GLD(sA0 + soff, wb + dc0);
        GLD(sB0 + soff, wb + 16384 + dc0);
        __builtin_amdgcn_s_barrier();
        __builtin_amdgcn_s_setprio(1);
#pragma unroll
        for (int mi = 0; mi < 4; ++mi)
#pragma unroll
            for (int ni = 0; ni < 4; ++ni)
                acc[mi][ni] = __builtin_amdgcn_mfma_f32_16x16x32_bf16(
                    bv[ni], av[mi], acc[mi][ni], 0, 0, 0);
        __builtin_amdgcn_s_setprio(0);

        // ---- ph2: read A-frags 4-7; stage A1,B1 of tile T+2; counted vmcnt
#pragma unroll
        for (int mi = 0; mi < 4; ++mi) aw[mi] = *(const bf16x8*)(rb + aoff[mi + 4]);
        GLD(sA1 + soff, wb + dc1);
        GLD(sB1 + soff, wb + 16384 + dc1);
        asm volatile("s_waitcnt vmcnt(4)" ::: "memory");   // tile T+1 landed
        __builtin_amdgcn_s_barrier();
        __builtin_amdgcn_s_setprio(1);
#pragma unroll
        for (int mi = 0; mi < 4; ++mi)
#pragma unroll
            for (int ni = 0; ni < 4; ++ni)
                acc[mi + 4][ni] = __builtin_amdgcn_mfma_f32_16x16x32_bf16(
                    bv[ni], aw[mi], acc[mi + 4][ni], 0, 0, 0);
        __builtin_amdgcn_s_setprio(0);

        rs = (rs == 2) ? 0 : rs + 1;
        ws = (ws == 2) ? 0 : ws + 1;
    }
#undef GLD

    // drain wrap-staged loads before block exit
    asm volatile("s_waitcnt vmcnt(0)" ::: "memory");

    // epilogue (round-6 verified). Operand-swapped D: n = frag + hi*4 + reg,
    // m = lo; 4 hi values cover 64 B contiguous per row -> full-sector writes.
    float* outp = out + ((size_t)bb * S_ + bm * 256 + wm * 128) * H_ + bn * 256 + wn * 64;
    const float* bp = bias + (size_t)c * H_ + bn * 256 + wn * 64;
#pragma unroll
    for (int ni = 0; ni < 4; ++ni) {
        const int nf = ni * 16 + hi * 4;
        const f32x4 b4 = *(const f32x4*)(bp + nf);
#pragma unroll
        for (int mi = 0; mi < 8; ++mi) {
            const int mf = mi * 16 + lo;
            f32x4 v = acc[mi][ni];
            v.x += b4.x; v.y += b4.y; v.z += b4.z; v.w += b4.w;
            __builtin_nontemporal_store(v, (f32x4*)(outp + (size_t)mf * H_ + nf));
        }
    }
}

// ---------------------------------------------------------------------------
// Fallback (ws too small): correct but slow f32 vector-ALU kernel.
__global__ __launch_bounds__(256) void fallback_kernel(
    const float* __restrict__ x, const int* __restrict__ cat,
    const float* __restrict__ W, const float* __restrict__ bias,
    float* __restrict__ out)
{
    __shared__ float xs[K_];
    int bs = blockIdx.x;
    int bb = bs >> 9;
    int c  = cat[bb];
    const float* xp = x + (size_t)bs * K_;
    for (int i = threadIdx.x; i < K_ / 4; i += 256)
        ((float4*)xs)[i] = ((const float4*)xp)[i];
    __syncthreads();

    int h = blockIdx.y * 1024 + threadIdx.x * 4;
    const float* Wp = W + (size_t)c * K_ * H_ + h;
    float a0 = 0.f, a1 = 0.f, a2 = 0.f, a3 = 0.f;
    for (int k = 0; k < K_; ++k) {
        float xv = xs[k];
        float4 wv = *(const float4*)(Wp + (size_t)k * H_);
        a0 += xv * wv.x; a1 += xv * wv.y; a2 += xv * wv.z; a3 += xv * wv.w;
    }
    float4 bv = *(const float4*)(bias + c * H_ + h);
    float4 o; o.x = a0 + bv.x; o.y = a1 + bv.y; o.z = a2 + bv.z; o.w = a3 + bv.w;
    *(float4*)(out + (size_t)bs * H_ + h) = o;
}

// ---------------------------------------------------------------------------
extern "C" void kernel_launch(void* const* d_in, const int* in_sizes, int n_in,
                              void* d_out, int out_size, void* d_ws, size_t ws_size,
                              hipStream_t stream) {
    const float* x        = (const float*)d_in[0];
    const void*  cat_raw  = d_in[1];
    const float* W        = (const float*)d_in[2];
    const float* bias     = (const float*)d_in[3];
    float*       out      = (float*)d_out;

    const size_t CAT_BYTES = 256;
    const size_t XB_OFF    = 256;
    const size_t XB_BYTES  = (size_t)B_ * S_ * K_ * 2;          // 64 MiB
    const size_t WT_OFF    = XB_OFF + XB_BYTES;
    const size_t WT_BYTES  = (size_t)C_ * H_ * K_ * 2;          // 256 MiB
    const size_t NEED      = WT_OFF + WT_BYTES;

    const int* catp;
    if (ws_size >= CAT_BYTES) {
        int* cat32 = (int*)d_ws;
        fix_cat_kernel<<<1, 64, 0, stream>>>(cat_raw, cat32);
        catp = cat32;
    } else {
        catp = (const int*)cat_raw;
    }

    if (ws_size >= NEED) {
        unsigned short* xb = (unsigned short*)((char*)d_ws + XB_OFF);
        unsigned short* WT = (unsigned short*)((char*)d_ws + WT_OFF);
        cvt_x_kernel<<<2048, 256, 0, stream>>>((const float4*)x, (uint4*)xb,
                                               (int)((size_t)B_ * S_ * K_ / 8));
        dim3 gw(64, 16, 32);
        cvt_w_kernel<<<gw, 256, 0, stream>>>(W, WT);
        (void)hipFuncSetAttribute((const void*)gemm6_kernel,
                                  hipFuncAttributeMaxDynamicSharedMemorySize, 98304);
        gemm6_kernel<<<2048, 512, 98304, stream>>>(xb, WT, bias, catp, out);
    } else {
        dim3 g(B_ * S_, H_ / 1024);
        fallback_kernel<<<g, 256, 0, stream>>>(x, catp, W, bias, out);
    }
}